// Round 1
// baseline (151.996 us; speedup 1.0000x reference)
//
#include <hip/hip_runtime.h>

#define NIN  128
#define NOUT 128
#define NN   256   // N
#define BB   4     // batch

typedef float v4f __attribute__((ext_vector_type(4)));

// ---------------- Kernel A: u{i,j}[b,o,j] = sum_c W{i,j}[o,c] * node[b,c,j] ----------------
// 512 blocks (one per b,o), 256 threads (one per j). Writes 2 x 512 KB to ws.
__global__ __launch_bounds__(256) void precompute_u(
    const float* __restrict__ node,  // [B,NIN,N]
    const float* __restrict__ Wi,    // [NOUT,NIN]
    const float* __restrict__ Wj,    // [NOUT,NIN]
    float* __restrict__ ui,          // [B*NOUT, N]
    float* __restrict__ uj)          // [B*NOUT, N]
{
    const int bo = blockIdx.x;
    const int b  = bo >> 7;
    const int o  = bo & (NOUT - 1);
    const int t  = threadIdx.x;

    const float* np_ = node + (size_t)b * NIN * NN + t;  // coalesced across lanes
    const float* wi  = Wi + o * NIN;                     // block-uniform -> scalar loads
    const float* wj  = Wj + o * NIN;

    float ai = 0.f, aj = 0.f;
    #pragma unroll 16
    for (int c = 0; c < NIN; ++c) {
        const float n = np_[c * NN];
        ai = fmaf(wi[c], n, ai);
        aj = fmaf(wj[c], n, aj);
    }
    ui[bo * NN + t] = ai;
    uj[bo * NN + t] = aj;
}

// ---------------- Kernel B2: out[b,o,i,j] = adj[b,i,j] * (i==j ? ui[j] : uj[j]) ------------
// Register-cache a 16-row adj chunk, emit OG=8 output channels from it.
// Grid: BB * (NOUT/OG) * (NN/16) = 4*16*16 = 1024 blocks, 256 threads.
// o-group is the fastest grid dim so neighboring blocks share the same adj chunk in L2.
// Nontemporal stores keep the 134 MB out-stream from evicting adj/ui/uj out of L2.
#define OG 8
#define RCH 16   // rows per block

__global__ __launch_bounds__(256) void stream_out_og(
    const float* __restrict__ adj,   // [B,1,N,N]
    const float* __restrict__ ui,    // [B*NOUT, N]
    const float* __restrict__ uj,    // [B*NOUT, N]
    float* __restrict__ out)         // [B,NOUT,N,N]
{
    const int blk = blockIdx.x;
    const int og  = blk & 15;          // o-group (fastest -> adj chunk L2 reuse)
    const int rc  = (blk >> 4) & 15;   // 16-row chunk
    const int b   = blk >> 8;

    const int t  = threadIdx.x;
    const int jb = (t & 63) << 2;      // column base (fixed per thread)
    const int rr = t >> 6;             // 0..3

    const float* adjb = adj + (size_t)b * (NN * NN);

    // Load this block's adj rows ONCE into registers (4 x float4 / thread).
    v4f a[4];
    #pragma unroll
    for (int r = 0; r < 4; ++r) {
        const int i = (rc << 4) + rr + (r << 2);
        a[r] = *(const v4f*)&adjb[i * NN + jb];
    }

    const int obase = b * NOUT + og * OG;

    #pragma unroll 2
    for (int o = 0; o < OG; ++o) {
        const int bo = obase + o;
        const v4f   vj  = *(const v4f*)&uj[bo * NN + jb];  // off-diagonal values
        const float* uip = ui + bo * NN;
        float*       outp = out + (size_t)bo * (NN * NN);

        #pragma unroll
        for (int r = 0; r < 4; ++r) {
            const int i = (rc << 4) + rr + (r << 2);
            const float s_ii = uip[i];                     // same addr across wave -> broadcast
            v4f v;
            v.x = (i == jb + 0) ? s_ii : vj.x;
            v.y = (i == jb + 1) ? s_ii : vj.y;
            v.z = (i == jb + 2) ? s_ii : vj.z;
            v.w = (i == jb + 3) ? s_ii : vj.w;
            const v4f rs = a[r] * v;
            __builtin_nontemporal_store(rs, (v4f*)&outp[i * NN + jb]);  // 1 KiB contiguous/wave
        }
    }
}

// ---------------- Fallback (ws too small): round-1 fused kernel --------------------------
__global__ __launch_bounds__(256) void nodeconv_fused(
    const float* __restrict__ adj, const float* __restrict__ node,
    const float* __restrict__ Wi, const float* __restrict__ Wj,
    float* __restrict__ out)
{
    __shared__ float si[NN];
    __shared__ float sj[NN];
    const int bo = blockIdx.x;
    const int b  = bo >> 7;
    const int o  = bo & (NOUT - 1);
    const int t  = threadIdx.x;
    {
        const float* np_ = node + (size_t)(b * NIN) * NN + t;
        const float* wi  = Wi + o * NIN;
        const float* wj  = Wj + o * NIN;
        float ai = 0.f, aj = 0.f;
        #pragma unroll 8
        for (int c = 0; c < NIN; ++c) {
            const float n = np_[(size_t)c * NN];
            ai += wi[c] * n;
            aj += wj[c] * n;
        }
        si[t] = ai;
        sj[t] = aj;
    }
    __syncthreads();
    const int jb   = (t & 63) << 2;
    const int rrow = t >> 6;
    const float4 vj = *(const float4*)&sj[jb];
    const float* adjb = adj + (size_t)b * (NN * NN);
    float*       outp = out + (size_t)bo * (NN * NN);
    #pragma unroll 4
    for (int r = 0; r < 64; ++r) {
        const int i = (r << 2) + rrow;
        const float s_ii = si[i];
        const float4 a = *(const float4*)&adjb[i * NN + jb];
        float4 v;
        v.x = (i == jb + 0) ? s_ii : vj.x;
        v.y = (i == jb + 1) ? s_ii : vj.y;
        v.z = (i == jb + 2) ? s_ii : vj.z;
        v.w = (i == jb + 3) ? s_ii : vj.w;
        float4 rs;
        rs.x = a.x * v.x; rs.y = a.y * v.y; rs.z = a.z * v.z; rs.w = a.w * v.w;
        *(float4*)&outp[i * NN + jb] = rs;
    }
}

extern "C" void kernel_launch(void* const* d_in, const int* in_sizes, int n_in,
                              void* d_out, int out_size, void* d_ws, size_t ws_size,
                              hipStream_t stream) {
    const float* adj  = (const float*)d_in[0];  // [4,1,256,256]
    const float* node = (const float*)d_in[1];  // [4,128,256]
    const float* Wi   = (const float*)d_in[2];  // [128,128]
    const float* Wj   = (const float*)d_in[3];  // [128,128]
    float* out = (float*)d_out;                 // [4,128,256,256]

    const size_t u_elems = (size_t)BB * NOUT * NN;          // 131072
    const size_t need    = 2 * u_elems * sizeof(float);     // 1 MiB

    if (ws_size >= need) {
        float* ui = (float*)d_ws;
        float* uj = ui + u_elems;
        precompute_u<<<dim3(BB * NOUT), dim3(256), 0, stream>>>(node, Wi, Wj, ui, uj);
        stream_out_og<<<dim3(BB * (NOUT / OG) * (NN / RCH)), dim3(256), 0, stream>>>(adj, ui, uj, out);
    } else {
        nodeconv_fused<<<dim3(BB * NOUT), dim3(256), 0, stream>>>(adj, node, Wi, Wj, out);
    }
}